// Round 1
// baseline (805.928 us; speedup 1.0000x reference)
//
#include <hip/hip_runtime.h>

typedef unsigned short u16;
typedef unsigned int u32;
typedef short bf16x8 __attribute__((ext_vector_type(8)));
typedef float f32x4 __attribute__((ext_vector_type(4)));

// ---- bf16 helpers ----
__device__ __forceinline__ u16 f2bf(float f) {
  union { float f; u32 i; } v; v.f = f;
  u32 x = v.i;
  return (u16)((x + 0x7fffu + ((x >> 16) & 1u)) >> 16);  // RNE
}

union Pack16 { u16 h[16]; float4 f4[2]; };
union F4U { float4 f; u32 u[4]; };

// ---- A-operand raw load (issue-only) + convert (consume) ----
// SRC 0: f32 row-major [.][1024], row m, 16 k-elems -> 4 float4 raw.
// SRC 1: bf16 Q-layout [N,H,S,DK]; m = n*1024+s; 16-run stays in one h;
//        raw uses r[0],r[1] only (16 bf16 = 2 float4).
template<int SRC>
__device__ __forceinline__ void loadA(const void* __restrict__ src, int m, int k, float4* r) {
  if constexpr (SRC == 0) {
    const float4* f = (const float4*)((const float*)src + (size_t)m * 1024 + k);
#pragma unroll
    for (int q = 0; q < 4; q++) r[q] = f[q];
  } else {
    const int n = m >> 10, s = m & 1023, h = k >> 6;
    const u16* b = (const u16*)src + ((size_t)((n * 16 + h) * 1024 + s)) * 64 + (k & 63);
    r[0] = *(const float4*)b;
    r[1] = *(const float4*)(b + 8);
  }
}

template<int SRC>
__device__ __forceinline__ void convA(const float4* r, Pack16& p) {
  if constexpr (SRC == 0) {
#pragma unroll
    for (int q = 0; q < 4; q++) {
      p.h[q * 4 + 0] = f2bf(r[q].x);
      p.h[q * 4 + 1] = f2bf(r[q].y);
      p.h[q * 4 + 2] = f2bf(r[q].z);
      p.h[q * 4 + 3] = f2bf(r[q].w);
    }
  } else {
    p.f4[0] = r[0];
    p.f4[1] = r[1];
  }
}

// =====================================================================
// GEMM: C[m][col] = sum_k A[m][k] * W[col][k] + bias[col]
// MODE 0 (proj): ASRC=0, m=s*8+n, out -> bf16 (u16) Q-layout [N,H,S,DK]
// MODE 1 (fc):   ASRC=1, m=n*1024+s, out -> f32 [S,N,D]  (d_out is float*!)
// 128x128 block tile, BK=32, 4 waves each 64x64 (4x4 MFMA tiles).
// K-step register prefetch: raw loads for step k+1 issued right after
// step k's registers are consumed by conversion (earliest WAR-safe
// point) -> ~full iteration of latency cover across both barriers.
// =====================================================================
template<int MODE, int ASRC>
__global__ __launch_bounds__(256, 2) void gemm_bt(const void* __restrict__ A,
                                                  const float* __restrict__ W,
                                                  const float* __restrict__ bias,
                                                  void* __restrict__ outv) {
  __shared__ __align__(16) u16 At[128 * 40];  // stride 40: rows 80B (16B aligned), banks 2-way
  __shared__ __align__(16) u16 Bt[128 * 40];

  const int tid = threadIdx.x;
  const int lane = tid & 63, wave = tid >> 6;
  const int quad = lane >> 4, l16 = lane & 15;
  const int bm = blockIdx.y * 128, bn = blockIdx.x * 128;
  const int wm = (wave >> 1) * 64, wn = (wave & 1) * 64;
  const int srow = tid >> 1;            // 0..127
  const int scol = (tid & 1) * 16;      // 0 or 16

  f32x4 acc[4][4];
#pragma unroll
  for (int i = 0; i < 4; i++)
#pragma unroll
    for (int j = 0; j < 4; j++) acc[i][j] = (f32x4){0.f, 0.f, 0.f, 0.f};

  u16* sA = At + srow * 40 + scol;
  u16* sB = Bt + srow * 40 + scol;

  float4 ra[4], rw[4];
  loadA<ASRC>(A, bm + srow, scol, ra);
  loadA<0>((const void*)W, bn + srow, scol, rw);

  for (int k0 = 0; k0 < 1024; k0 += 32) {
    Pack16 pa, pb;
    convA<ASRC>(ra, pa);   // waits on loads issued one full iteration ago
    convA<0>(rw, pb);
    if (k0 + 32 < 1024) {  // prefetch next K-step (registers now free)
      loadA<ASRC>(A, bm + srow, scol + k0 + 32, ra);
      loadA<0>((const void*)W, bn + srow, scol + k0 + 32, rw);
    }
    __syncthreads();
    *(float4*)(sA) = pa.f4[0]; *(float4*)(sA + 8) = pa.f4[1];
    *(float4*)(sB) = pb.f4[0]; *(float4*)(sB + 8) = pb.f4[1];
    __syncthreads();

    bf16x8 af[4], bfr[4];
#pragma unroll
    for (int mt = 0; mt < 4; mt++)
      af[mt] = *(const bf16x8*)(At + (wm + mt * 16 + l16) * 40 + quad * 8);
#pragma unroll
    for (int nt = 0; nt < 4; nt++)
      bfr[nt] = *(const bf16x8*)(Bt + (wn + nt * 16 + l16) * 40 + quad * 8);
#pragma unroll
    for (int mt = 0; mt < 4; mt++)
#pragma unroll
      for (int nt = 0; nt < 4; nt++)
        acc[mt][nt] = __builtin_amdgcn_mfma_f32_16x16x32_bf16(af[mt], bfr[nt], acc[mt][nt], 0, 0, 0);
  }

#pragma unroll
  for (int mt = 0; mt < 4; mt++) {
#pragma unroll
    for (int nt = 0; nt < 4; nt++) {
      const int col = bn + wn + nt * 16 + l16;
      const float bv = bias[col];
#pragma unroll
      for (int i = 0; i < 4; i++) {
        const int row = bm + wm + mt * 16 + quad * 4 + i;
        const float v = acc[mt][nt][i] + bv;
        if (MODE == 0) {
          const int s = row >> 3, n = row & 7;
          const int h = col >> 6, dk = col & 63;
          ((u16*)outv)[(size_t)(((n * 16 + h) * 1024 + s) * 64 + dk)] = f2bf(v);
        } else {
          const int n = row >> 10, s = row & 1023;
          ((float*)outv)[(size_t)((s * 8 + n) * 1024 + col)] = v;  // f32 output!
        }
      }
    }
  }
}

// =====================================================================
// Flash attention, IN-PLACE: QC holds Q in [N,H,S,DK] bf16 on entry;
// ctx is written back into the same slab (each block's Q rows are
// loaded to registers before any write; slabs are block-private).
// Block: 256 thr = 4 waves, 64 queries (16/wave), key tiles of 64.
// grid: (16 qtiles, 128 nh)
// =====================================================================
__global__ __launch_bounds__(256, 2) void attn_kernel(u16* __restrict__ QC,
                                                      const u16* __restrict__ K,
                                                      const u16* __restrict__ V,
                                                      const int* __restrict__ mask) {
  __shared__ __align__(16) u16 Ks[64 * 72];     // [key][dk], stride 72
  __shared__ __align__(16) u16 Vs[64 * 66];     // [key][dk], stride 66 (conflict-free col gather)
  __shared__ __align__(16) u16 Ps[4 * 16 * 72]; // per-wave P tile [16][72]
  __shared__ float mbias[64];

  const int tid = threadIdx.x;
  const int lane = tid & 63, wave = tid >> 6;
  const int quad = lane >> 4, l16 = lane & 15;
  const int qt = blockIdx.x, nh = blockIdx.y;
  const int n = nh >> 4;
  const size_t base = (size_t)nh << 16;  // nh * 1024*64

  // Q fragments (A-operand layout), held in regs all kernel
  const int q0 = qt * 64 + wave * 16;
  bf16x8 qf0, qf1;
  {
    const u16* qp = QC + base + (size_t)(q0 + l16) * 64 + quad * 8;
    qf0 = *(const bf16x8*)qp;
    qf1 = *(const bf16x8*)(qp + 32);
  }

  float m_i[4], l_i[4];
  f32x4 o[4];
#pragma unroll
  for (int i = 0; i < 4; i++) { m_i[i] = -1e30f; l_i[i] = 0.f; }
#pragma unroll
  for (int d = 0; d < 4; d++) o[d] = (f32x4){0.f, 0.f, 0.f, 0.f};

  const int sr = tid >> 2;           // 0..63
  const int sc = (tid & 3) * 16;     // 0,16,32,48
  const u16* kbase = K + base + (size_t)sr * 64 + sc;
  const u16* vbase = V + base + (size_t)sr * 64 + sc;
  u16* pw = Ps + wave * (16 * 72);

  for (int kt = 0; kt < 16; kt++) {
    // ---- stage K, V tiles + mask bias ----
    float4 kv0 = *(const float4*)(kbase + kt * 64 * 64);
    float4 kv1 = *(const float4*)(kbase + kt * 64 * 64 + 8);
    F4U vv0, vv1;
    vv0.f = *(const float4*)(vbase + kt * 64 * 64);
    vv1.f = *(const float4*)(vbase + kt * 64 * 64 + 8);
    int mk = (tid < 64) ? mask[n * 1024 + kt * 64 + tid] : 0;
    __syncthreads();  // protect previous iteration's LDS reads
    *(float4*)(Ks + sr * 72 + sc) = kv0;
    *(float4*)(Ks + sr * 72 + sc + 8) = kv1;
    {
      u32* vd = (u32*)(Vs + sr * 66 + sc);  // byte addr 132*sr + 2*sc ≡ 0 mod 4
#pragma unroll
      for (int j = 0; j < 4; j++) vd[j] = vv0.u[j];
#pragma unroll
      for (int j = 0; j < 4; j++) vd[4 + j] = vv1.u[j];
    }
    if (tid < 64) mbias[tid] = mk ? -1e30f : 0.0f;
    __syncthreads();

    // ---- S = Q K^T / 8 + mask ----
    f32x4 sfr[4];
#pragma unroll
    for (int nt = 0; nt < 4; nt++) {
      bf16x8 b0 = *(const bf16x8*)(Ks + (nt * 16 + l16) * 72 + quad * 8);
      bf16x8 b1 = *(const bf16x8*)(Ks + (nt * 16 + l16) * 72 + 32 + quad * 8);
      f32x4 a = (f32x4){0.f, 0.f, 0.f, 0.f};
      a = __builtin_amdgcn_mfma_f32_16x16x32_bf16(qf0, b0, a, 0, 0, 0);
      a = __builtin_amdgcn_mfma_f32_16x16x32_bf16(qf1, b1, a, 0, 0, 0);
      sfr[nt] = a;
    }
    float mb[4];
#pragma unroll
    for (int nt = 0; nt < 4; nt++) mb[nt] = mbias[nt * 16 + l16];
#pragma unroll
    for (int nt = 0; nt < 4; nt++)
#pragma unroll
      for (int i = 0; i < 4; i++)
        sfr[nt][i] = sfr[nt][i] * 0.125f + mb[nt];

    // ---- online softmax: row = quad*4+i lives in this 16-lane group ----
    float alpha[4];
#pragma unroll
    for (int i = 0; i < 4; i++) {
      float m = fmaxf(fmaxf(sfr[0][i], sfr[1][i]), fmaxf(sfr[2][i], sfr[3][i]));
#pragma unroll
      for (int off = 1; off < 16; off <<= 1) m = fmaxf(m, __shfl_xor(m, off, 64));
      float mn = fmaxf(m_i[i], m);
      alpha[i] = __expf(m_i[i] - mn);
      m_i[i] = mn;
    }
    float rs[4] = {0.f, 0.f, 0.f, 0.f};
#pragma unroll
    for (int nt = 0; nt < 4; nt++) {
#pragma unroll
      for (int i = 0; i < 4; i++) {
        float p = __expf(sfr[nt][i] - m_i[i]);
        rs[i] += p;
        pw[(quad * 4 + i) * 72 + nt * 16 + l16] = f2bf(p);
      }
    }
#pragma unroll
    for (int i = 0; i < 4; i++) {
      float s = rs[i];
#pragma unroll
      for (int off = 1; off < 16; off <<= 1) s += __shfl_xor(s, off, 64);
      l_i[i] = l_i[i] * alpha[i] + s;
    }
#pragma unroll
    for (int d = 0; d < 4; d++)
#pragma unroll
      for (int i = 0; i < 4; i++) o[d][i] *= alpha[i];
    __syncthreads();  // P tile visible (also orders vs next staging)

    // ---- O += P @ V ----
#pragma unroll
    for (int ks = 0; ks < 2; ks++) {
      bf16x8 pa = *(const bf16x8*)(pw + l16 * 72 + ks * 32 + quad * 8);
#pragma unroll
      for (int d = 0; d < 4; d++) {
        bf16x8 vb;
#pragma unroll
        for (int j = 0; j < 8; j++)
          vb[j] = (short)Vs[(ks * 32 + quad * 8 + j) * 66 + d * 16 + l16];
        o[d] = __builtin_amdgcn_mfma_f32_16x16x32_bf16(pa, vb, o[d], 0, 0, 0);
      }
    }
  }

  // ---- epilogue: write ctx IN-PLACE into the block's own Q slab ----
#pragma unroll
  for (int i = 0; i < 4; i++) {
    const float inv = 1.0f / l_i[i];
    const int q = q0 + quad * 4 + i;
    const size_t ob = base + (size_t)q * 64;
#pragma unroll
    for (int d = 0; d < 4; d++)
      QC[ob + d * 16 + l16] = f2bf(o[d][i] * inv);
  }
}

// =====================================================================
extern "C" void kernel_launch(void* const* d_in, const int* in_sizes, int n_in,
                              void* d_out, int out_size, void* d_ws, size_t ws_size,
                              hipStream_t stream) {
  // Contract: float inputs f32, mask int32, OUTPUT f32 (reference returns f32).
  const void* Qpoi = d_in[0];
  const void* Qsvi = d_in[1];
  const void* Kin  = d_in[2];
  const void* Vin  = d_in[3];
  const int* mask  = (const int*)d_in[4];
  const float* wq_poi_w = (const float*)d_in[5];
  const float* wq_poi_b = (const float*)d_in[6];
  const float* wq_svi_w = (const float*)d_in[7];
  const float* wq_svi_b = (const float*)d_in[8];
  const float* wk_w = (const float*)d_in[9];
  const float* wk_b = (const float*)d_in[10];
  const float* wv_w = (const float*)d_in[11];
  const float* wv_b = (const float*)d_in[12];
  const float* fc_w = (const float*)d_in[13];
  const float* fc_b = (const float*)d_in[14];

  const size_t SZ = (size_t)8 * 16 * 1024 * 64;  // 8388608 elements per output half
  u16* W0 = (u16*)d_ws;        // bf16 slab 0: Kh, later poi-ctx bounce (16.78 MB)
  u16* W1 = W0 + SZ;           // bf16 slab 1: Vh                        (16.78 MB)
  float* Of = (float*)d_out;   // f32 [2][SZ]
  u16* Qs = (u16*)d_out;       // bf16 scratch in out-half-0 region (first 16.78 MB of 33.5)

  dim3 gg(8, 64), bb(256, 1, 1);
  dim3 ga(16, 128);

  // shared K/V projections -> ws (bf16 head layout)
  hipLaunchKernelGGL((gemm_bt<0, 0>), gg, bb, 0, stream, Kin, wk_w, wk_b, (void*)W0);
  hipLaunchKernelGGL((gemm_bt<0, 0>), gg, bb, 0, stream, Vin, wv_w, wv_b, (void*)W1);

  // ---- svi path: scratch in out-half-0 region, fc writes f32 half 1 ----
  hipLaunchKernelGGL((gemm_bt<0, 0>), gg, bb, 0, stream, Qsvi, wq_svi_w, wq_svi_b, (void*)Qs);
  hipLaunchKernelGGL(attn_kernel, ga, bb, 0, stream, Qs, W0, W1, mask);   // ctx in-place
  hipLaunchKernelGGL((gemm_bt<1, 1>), gg, bb, 0, stream, (const void*)Qs, fc_w, fc_b, (void*)(Of + SZ));

  // ---- poi path: scratch again, bounce ctx into W0 (Kh dead), fc -> f32 half 0 ----
  hipLaunchKernelGGL((gemm_bt<0, 0>), gg, bb, 0, stream, Qpoi, wq_poi_w, wq_poi_b, (void*)Qs);
  hipLaunchKernelGGL(attn_kernel, ga, bb, 0, stream, Qs, W0, W1, mask);   // ctx in-place
  hipMemcpyAsync(W0, Qs, SZ * sizeof(u16), hipMemcpyDeviceToDevice, stream);
  hipLaunchKernelGGL((gemm_bt<1, 1>), gg, bb, 0, stream, (const void*)W0, fc_w, fc_b, (void*)Of);
}